// Round 1
// baseline (915.678 us; speedup 1.0000x reference)
//
#include <hip/hip_runtime.h>
#include <math.h>

#define Tn 2048
#define Dn 1024
#define Hn 16
#define Sn 64
#define LVn 12
#define HDn 64

__device__ __forceinline__ float softplus_f(float z) {
  // stable log1p(exp(z))
  return (z > 0.f) ? (z + log1pf(expf(-z))) : log1pf(expf(z));
}

__device__ __forceinline__ float f4c(const float4& v, int j) {
  return j == 0 ? v.x : j == 1 ? v.y : j == 2 ? v.z : v.w;
}

// ---------------- GEMM: C[M,N] = X[M,K] * W[N,K]^T (+ optional residual R) -----
// M = Tn, N = Dn, K = Dn fixed. 64x64 tile, BK=16, 256 threads, 4x4 per thread.
__device__ __forceinline__ void gemm_body(const float* __restrict__ X,
                                          const float* __restrict__ W,
                                          const float* __restrict__ R,
                                          float* __restrict__ C) {
  __shared__ float Xs[16][68];
  __shared__ float Ws[16][68];
  const int bm = blockIdx.x * 64, bn = blockIdx.y * 64;
  const int tid = threadIdx.x;
  const int tx = tid & 15, ty = tid >> 4;
  float acc[4][4] = {};
  for (int k0 = 0; k0 < Dn; k0 += 16) {
#pragma unroll
    for (int i = 0; i < 4; ++i) {
      int idx = tid + i * 256;
      int r = idx >> 4, kk = idx & 15;
      Xs[kk][r] = X[(bm + r) * Dn + k0 + kk];
      Ws[kk][r] = W[(bn + r) * Dn + k0 + kk];
    }
    __syncthreads();
#pragma unroll
    for (int kk = 0; kk < 16; ++kk) {
      const float4 a = *(const float4*)&Xs[kk][ty * 4];
      const float4 b = *(const float4*)&Ws[kk][tx * 4];
      acc[0][0] += a.x * b.x; acc[0][1] += a.x * b.y; acc[0][2] += a.x * b.z; acc[0][3] += a.x * b.w;
      acc[1][0] += a.y * b.x; acc[1][1] += a.y * b.y; acc[1][2] += a.y * b.z; acc[1][3] += a.y * b.w;
      acc[2][0] += a.z * b.x; acc[2][1] += a.z * b.y; acc[2][2] += a.z * b.z; acc[2][3] += a.z * b.w;
      acc[3][0] += a.w * b.x; acc[3][1] += a.w * b.y; acc[3][2] += a.w * b.z; acc[3][3] += a.w * b.w;
    }
    __syncthreads();
  }
#pragma unroll
  for (int i = 0; i < 4; ++i) {
    const int m = bm + ty * 4 + i, n = bn + tx * 4;
    float4 v = make_float4(acc[i][0], acc[i][1], acc[i][2], acc[i][3]);
    if (R) {
      const float4 rv = *(const float4*)&R[m * Dn + n];
      v.x += rv.x; v.y += rv.y; v.z += rv.z; v.w += rv.w;
    }
    *(float4*)&C[m * Dn + n] = v;
  }
}

__global__ __launch_bounds__(256) void gemm_qkv_k(
    const float* __restrict__ X, const float* __restrict__ Wq,
    const float* __restrict__ Wk, const float* __restrict__ Wv,
    float* __restrict__ Qo, float* __restrict__ Ko, float* __restrict__ Vo) {
  const float* W = blockIdx.z == 0 ? Wq : blockIdx.z == 1 ? Wk : Wv;
  float* C = blockIdx.z == 0 ? Qo : blockIdx.z == 1 ? Ko : Vo;
  gemm_body(X, W, nullptr, C);
}

__global__ __launch_bounds__(256) void gemm_out_k(
    const float* __restrict__ X, const float* __restrict__ W,
    const float* __restrict__ R, float* __restrict__ C) {
  gemm_body(X, W, R, C);
}

// ---------------- small projections: Lam[t,h,l], g[t,h] ----------------------
__global__ __launch_bounds__(256) void proj_small_k(
    const float* __restrict__ x, const float* __restrict__ Wdl,
    const float* __restrict__ Wdt, const float* __restrict__ A_log,
    const float* __restrict__ dt_bias, const float* __restrict__ Lp,
    float* __restrict__ Lam, float* __restrict__ g) {
  const int t = blockIdx.x;
  __shared__ float xs[Dn];
  const int tid = threadIdx.x;
  ((float4*)xs)[tid] = ((const float4*)(x + t * Dn))[tid];
  __syncthreads();
  if (tid < Hn * LVn + Hn) {  // 208 dot products of length 1024
    const float* wrow = (tid < Hn * LVn) ? (Wdl + tid * Dn) : (Wdt + (tid - Hn * LVn) * Dn);
    const float4* w4 = (const float4*)wrow;
    const float4* x4 = (const float4*)xs;
    float acc = 0.f;
    for (int k = 0; k < Dn / 4; ++k) {
      const float4 a = x4[k], b = w4[k];
      acc += a.x * b.x + a.y * b.y + a.z * b.z + a.w * b.w;
    }
    if (tid < Hn * LVn) {
      const int hh = tid / LVn, ll = tid % LVn;
      Lam[(t * Hn + hh) * LVn + ll] = softplus_f(Lp[hh * LVn + ll] * acc);
    } else {
      const int hh = tid - Hn * LVn;
      const float dtv = softplus_f(acc + dt_bias[hh]);
      g[t * Hn + hh] = -expf(A_log[hh]) * dtv;
    }
  }
}

// ---------------- cumsum of g over t (double precision) ----------------------
__global__ void cumsum_k(const float* __restrict__ g, double* __restrict__ cg) {
  const int h = threadIdx.x;
  if (h < Hn) {
    double a = 0.0;
    for (int t = 0; t < Tn; ++t) {
      a += (double)g[t * Hn + h];
      cg[t * Hn + h] = a;
    }
  }
}

// ---------------- gated causal attention core --------------------------------
__global__ __launch_bounds__(256, 2) void attn_k(
    const float* __restrict__ Q, const float* __restrict__ Km,
    const float* __restrict__ Vm, const double* __restrict__ cg,
    const float* __restrict__ Lam, float* __restrict__ Y) {
  const int h = blockIdx.y;
  const int t0 = blockIdx.x * 64;
  __shared__ float Qs[64][68], Ks[64][68], Vs[64][68], Ps[64][68];
  __shared__ double cgT[64], cgS[64];
  __shared__ float lamT[64][LVn];
  const int tid = threadIdx.x;
  const int tx = tid & 15, ty = tid >> 4;

#pragma unroll
  for (int i = 0; i < 4; ++i) {
    int idx = tid + i * 256;
    int r = idx >> 4, d4 = (idx & 15) * 4;
    *(float4*)&Qs[r][d4] = *(const float4*)&Q[(t0 + r) * Dn + h * Sn + d4];
  }
  if (tid < 64) cgT[tid] = cg[(t0 + tid) * Hn + h];
  for (int i = tid; i < 64 * LVn; i += 256) {
    int r = i / LVn, l = i % LVn;
    lamT[r][l] = Lam[((t0 + r) * Hn + h) * LVn + l];
  }

  float accY[4][4] = {};

  for (int s0 = t0; s0 >= 0; s0 -= 64) {
    __syncthreads();  // previous iteration readers done; also covers prologue staging
#pragma unroll
    for (int i = 0; i < 4; ++i) {
      int idx = tid + i * 256;
      int r = idx >> 4, d4 = (idx & 15) * 4;
      *(float4*)&Ks[r][d4] = *(const float4*)&Km[(s0 + r) * Dn + h * Sn + d4];
      *(float4*)&Vs[r][d4] = *(const float4*)&Vm[(s0 + r) * Dn + h * HDn + d4];
    }
    if (tid < 64) cgS[tid] = cg[(s0 + tid) * Hn + h];
    __syncthreads();

    // monotone decay: all remaining tiles contribute < e^-80 ~ 1.8e-35 -> stop
    if (s0 + 64 <= t0 && (float)(cgT[0] - cgS[63]) < -80.f) break;

    // scores: sc[i][j] = Q[t0+ty*4+i] . K[s0+tx*4+j]
    float sc[4][4] = {};
#pragma unroll
    for (int d = 0; d < 64; d += 4) {
      float4 a[4], b[4];
#pragma unroll
      for (int i = 0; i < 4; ++i) a[i] = *(const float4*)&Qs[ty * 4 + i][d];
#pragma unroll
      for (int j = 0; j < 4; ++j) b[j] = *(const float4*)&Ks[tx * 4 + j][d];
#pragma unroll
      for (int i = 0; i < 4; ++i)
#pragma unroll
        for (int j = 0; j < 4; ++j)
          sc[i][j] += a[i].x * b[j].x + a[i].y * b[j].y + a[i].z * b[j].z + a[i].w * b[j].w;
    }

    // gate: w = sc * S^-0.5 * exp(cg_t - cg_s) * Lam[t,h,level(t,s)], causal
#pragma unroll
    for (int i = 0; i < 4; ++i) {
      const int t = t0 + ty * 4 + i;
      float w[4];
#pragma unroll
      for (int j = 0; j < 4; ++j) {
        const int s = s0 + tx * 4 + j;
        float val = 0.f;
        if (s <= t) {
          const float dd = (float)(cgT[ty * 4 + i] - cgS[tx * 4 + j]);
          const int xr = t ^ s;
          const int lvl = xr ? (32 - __clz(xr)) : 0;
          val = sc[i][j] * 0.125f * expf(dd) * lamT[ty * 4 + i][lvl];
        }
        w[j] = val;
      }
      *(float4*)&Ps[ty * 4 + i][tx * 4] = make_float4(w[0], w[1], w[2], w[3]);
    }
    __syncthreads();

    // PV: accY[i][j] += sum_ss Ps[ty*4+i][ss] * Vs[ss][tx*4+j]
#pragma unroll
    for (int ss4 = 0; ss4 < 64; ss4 += 4) {
      float4 v[4];
#pragma unroll
      for (int q = 0; q < 4; ++q) v[q] = *(const float4*)&Vs[ss4 + q][tx * 4];
#pragma unroll
      for (int i = 0; i < 4; ++i) {
        const float4 p = *(const float4*)&Ps[ty * 4 + i][ss4];
#pragma unroll
        for (int j = 0; j < 4; ++j) {
          accY[i][j] += p.x * f4c(v[0], j) + p.y * f4c(v[1], j) +
                        p.z * f4c(v[2], j) + p.w * f4c(v[3], j);
        }
      }
    }
  }

#pragma unroll
  for (int i = 0; i < 4; ++i) {
    *(float4*)&Y[(t0 + ty * 4 + i) * Dn + h * HDn + tx * 4] =
        make_float4(accY[i][0], accY[i][1], accY[i][2], accY[i][3]);
  }
}

// ---------------- layernorm (in-place on d_out) -------------------------------
__global__ __launch_bounds__(256) void ln_k(float* __restrict__ io,
                                            const float* __restrict__ gw,
                                            const float* __restrict__ bw) {
  const int t = blockIdx.x;
  const int tid = threadIdx.x;
  const float4 v = ((const float4*)(io + t * Dn))[tid];
  float s = v.x + v.y + v.z + v.w;
  float q = v.x * v.x + v.y * v.y + v.z * v.z + v.w * v.w;
#pragma unroll
  for (int off = 32; off >= 1; off >>= 1) {
    s += __shfl_down(s, off);
    q += __shfl_down(q, off);
  }
  __shared__ float sm[4], qm[4];
  const int w = tid >> 6, lane = tid & 63;
  if (lane == 0) { sm[w] = s; qm[w] = q; }
  __syncthreads();
  const float S_ = sm[0] + sm[1] + sm[2] + sm[3];
  const float Q_ = qm[0] + qm[1] + qm[2] + qm[3];
  const float mu = S_ * (1.f / Dn);
  const float var = Q_ * (1.f / Dn) - mu * mu;
  const float inv = rsqrtf(var + 1e-5f);
  const float4 gg = ((const float4*)gw)[tid];
  const float4 bb = ((const float4*)bw)[tid];
  float4 o;
  o.x = (v.x - mu) * inv * gg.x + bb.x;
  o.y = (v.y - mu) * inv * gg.y + bb.y;
  o.z = (v.z - mu) * inv * gg.z + bb.z;
  o.w = (v.w - mu) * inv * gg.w + bb.w;
  ((float4*)(io + t * Dn))[tid] = o;
}

extern "C" void kernel_launch(void* const* d_in, const int* in_sizes, int n_in,
                              void* d_out, int out_size, void* d_ws, size_t ws_size,
                              hipStream_t stream) {
  (void)in_sizes; (void)n_in; (void)out_size; (void)ws_size;
  const float* x      = (const float*)d_in[0];
  const float* Wq     = (const float*)d_in[1];
  const float* Wk     = (const float*)d_in[2];
  const float* Wv     = (const float*)d_in[3];
  const float* Wdl    = (const float*)d_in[4];
  const float* Wdt    = (const float*)d_in[5];
  const float* Wout   = (const float*)d_in[6];
  const float* A_log  = (const float*)d_in[7];
  const float* dt_bias= (const float*)d_in[8];
  const float* Lp     = (const float*)d_in[9];
  const float* ln_g   = (const float*)d_in[10];
  const float* ln_b   = (const float*)d_in[11];
  float* out = (float*)d_out;
  float* ws  = (float*)d_ws;

  const size_t MAT = (size_t)Tn * Dn;  // 2M floats
  float*  Qb   = ws;
  float*  Kb   = ws + MAT;
  float*  Vb   = ws + 2 * MAT;
  float*  Yb   = ws + 3 * MAT;
  float*  gb   = ws + 4 * MAT;                  // Tn*Hn floats
  double* cgd  = (double*)(ws + 4 * MAT + Tn * Hn);   // Tn*Hn doubles (64KB*4)
  float*  Lamb = ws + 4 * MAT + Tn * Hn + 2 * Tn * Hn; // Tn*Hn*LVn floats

  gemm_qkv_k<<<dim3(Tn / 64, Dn / 64, 3), 256, 0, stream>>>(x, Wq, Wk, Wv, Qb, Kb, Vb);
  proj_small_k<<<dim3(Tn), 256, 0, stream>>>(x, Wdl, Wdt, A_log, dt_bias, Lp, Lamb, gb);
  cumsum_k<<<1, 64, 0, stream>>>(gb, cgd);
  attn_k<<<dim3(Tn / 64, Hn), 256, 0, stream>>>(Qb, Kb, Vb, cgd, Lamb, Yb);
  gemm_out_k<<<dim3(Tn / 64, Dn / 64), 256, 0, stream>>>(Yb, Wout, x, out);
  ln_k<<<dim3(Tn), 256, 0, stream>>>(out, ln_g, ln_b);
}

// Round 4
// 412.296 us; speedup vs baseline: 2.2209x; 2.2209x over previous
//
#include <hip/hip_runtime.h>
#include <math.h>

#define Tn 2048
#define Dn 1024
#define Hn 16
#define Sn 64
#define LVn 12
#define HDn 64

typedef short short8 __attribute__((ext_vector_type(8)));
typedef unsigned short ushortv8 __attribute__((ext_vector_type(8)));
typedef float floatx4 __attribute__((ext_vector_type(4)));

__device__ __forceinline__ float softplus_f(float z) {
  return (z > 0.f) ? (z + log1pf(expf(-z))) : log1pf(expf(z));
}

__device__ __forceinline__ unsigned short f2bf(float f) {
  union { float f; unsigned u; } v; v.f = f;
  unsigned r = v.u + 0x7FFF + ((v.u >> 16) & 1);  // RNE
  return (unsigned short)(r >> 16);
}

__device__ __forceinline__ void gld16(const void* g, void* l) {
  __builtin_amdgcn_global_load_lds(
      (const __attribute__((address_space(1))) unsigned int*)g,
      (__attribute__((address_space(3))) unsigned int*)l, 16, 0, 0);
}

// ---------------- fp32 -> bf16 conversions (x, Wq, Wk, Wv, Wout) -------------
__global__ __launch_bounds__(256) void cvt5_k(
    const float* __restrict__ x, unsigned short* __restrict__ xb,
    const float* __restrict__ w0, unsigned short* __restrict__ w0b,
    const float* __restrict__ w1, unsigned short* __restrict__ w1b,
    const float* __restrict__ w2, unsigned short* __restrict__ w2b,
    const float* __restrict__ w3, unsigned short* __restrict__ w3b) {
  const int seg = blockIdx.y;
  const float* s; unsigned short* d;
  if (seg == 0)      { s = x;  d = xb;  }
  else if (seg == 1) { s = w0; d = w0b; }
  else if (seg == 2) { s = w1; d = w1b; }
  else if (seg == 3) { s = w2; d = w2b; }
  else               { s = w3; d = w3b; }
  const int i = (blockIdx.x * 256 + threadIdx.x) * 8;
  const float4 u0 = *(const float4*)&s[i];
  const float4 u1 = *(const float4*)&s[i + 4];
  ushortv8 o;
  o[0] = f2bf(u0.x); o[1] = f2bf(u0.y); o[2] = f2bf(u0.z); o[3] = f2bf(u0.w);
  o[4] = f2bf(u1.x); o[5] = f2bf(u1.y); o[6] = f2bf(u1.z); o[7] = f2bf(u1.w);
  *(ushortv8*)&d[i] = o;
}

__global__ __launch_bounds__(256) void cvt1_k(const float* __restrict__ s,
                                              unsigned short* __restrict__ d) {
  const int i = (blockIdx.x * 256 + threadIdx.x) * 8;
  const float4 u0 = *(const float4*)&s[i];
  const float4 u1 = *(const float4*)&s[i + 4];
  ushortv8 o;
  o[0] = f2bf(u0.x); o[1] = f2bf(u0.y); o[2] = f2bf(u0.z); o[3] = f2bf(u0.w);
  o[4] = f2bf(u1.x); o[5] = f2bf(u1.y); o[6] = f2bf(u1.z); o[7] = f2bf(u1.w);
  *(ushortv8*)&d[i] = o;
}

// ---------------- bf16 MFMA GEMM: C[m][n] = sum_k A[m][k]*B[n][k] (+R) -------
// 128x128 tile, BK=32, 256 threads = 4 waves (2x2), 16x16x32 bf16 MFMA.
__global__ __launch_bounds__(256) void mfma_gemm_k(
    const unsigned short* __restrict__ A,
    const unsigned short* __restrict__ B0, const unsigned short* __restrict__ B1,
    const unsigned short* __restrict__ B2,
    const float* __restrict__ R,
    float* __restrict__ C0, float* __restrict__ C1, float* __restrict__ C2) {
  const unsigned short* B = blockIdx.z == 0 ? B0 : blockIdx.z == 1 ? B1 : B2;
  float* C = blockIdx.z == 0 ? C0 : blockIdx.z == 1 ? C1 : C2;
  __shared__ unsigned short lA[128 * 32];
  __shared__ unsigned short lB[128 * 32];
  const int tid = threadIdx.x;
  const int bm = blockIdx.x * 128, bn = blockIdx.y * 128;
  const int lane = tid & 63, wave = tid >> 6;
  const int wm = wave >> 1, wn = wave & 1;
  const int l16 = lane & 15, lk = lane >> 4;
  const int sr = tid >> 2, sc = (tid & 3) * 8;  // staging row/col
  floatx4 acc[4][4] = {};
  for (int k0 = 0; k0 < Dn; k0 += 32) {
    __syncthreads();  // previous tile's readers done
    gld16(&A[(size_t)(bm + sr) * Dn + k0 + sc],      &lA[tid * 8]);
    gld16(&A[(size_t)(bm + 64 + sr) * Dn + k0 + sc], &lA[2048 + tid * 8]);
    gld16(&B[(size_t)(bn + sr) * Dn + k0 + sc],      &lB[tid * 8]);
    gld16(&B[(size_t)(bn + 64 + sr) * Dn + k0 + sc], &lB[2048 + tid * 8]);
    __syncthreads();  // drains vmcnt: LDS tile ready
    short8 a[4], b[4];
#pragma unroll
    for (int mf = 0; mf < 4; ++mf)
      a[mf] = *(const short8*)&lA[(wm * 64 + mf * 16 + l16) * 32 + lk * 8];
#pragma unroll
    for (int nf = 0; nf < 4; ++nf)
      b[nf] = *(const short8*)&lB[(wn * 64 + nf * 16 + l16) * 32 + lk * 8];
#pragma unroll
    for (int mf = 0; mf < 4; ++mf)
#pragma unroll
      for (int nf = 0; nf < 4; ++nf)
        acc[mf][nf] = __builtin_amdgcn_mfma_f32_16x16x32_bf16(
            a[mf], b[nf], acc[mf][nf], 0, 0, 0);
  }
  // epilogue: D mapping col=lane&15, row=(lane>>4)*4+reg
#pragma unroll
  for (int mf = 0; mf < 4; ++mf) {
#pragma unroll
    for (int nf = 0; nf < 4; ++nf) {
      const int col = bn + wn * 64 + nf * 16 + l16;
#pragma unroll
      for (int r = 0; r < 4; ++r) {
        const int row = bm + wm * 64 + mf * 16 + lk * 4 + r;
        float v = acc[mf][nf][r];
        if (R) v += R[(size_t)row * Dn + col];
        C[(size_t)row * Dn + col] = v;
      }
    }
  }
}

// ---------------- small projections: Lam[t,h,l], g[t,h] ----------------------
__global__ __launch_bounds__(256) void proj_small_k(
    const float* __restrict__ x, const float* __restrict__ Wdl,
    const float* __restrict__ Wdt, const float* __restrict__ A_log,
    const float* __restrict__ dt_bias, const float* __restrict__ Lp,
    float* __restrict__ Lam, float* __restrict__ g) {
  const int t = blockIdx.x;
  __shared__ float xs[Dn];
  const int tid = threadIdx.x;
  ((float4*)xs)[tid] = ((const float4*)(x + t * Dn))[tid];
  __syncthreads();
  if (tid < Hn * LVn + Hn) {
    const float* wrow = (tid < Hn * LVn) ? (Wdl + tid * Dn) : (Wdt + (tid - Hn * LVn) * Dn);
    const float4* w4 = (const float4*)wrow;
    const float4* x4 = (const float4*)xs;
    float acc = 0.f;
    for (int k = 0; k < Dn / 4; ++k) {
      const float4 a = x4[k], b = w4[k];
      acc += a.x * b.x + a.y * b.y + a.z * b.z + a.w * b.w;
    }
    if (tid < Hn * LVn) {
      const int hh = tid / LVn, ll = tid % LVn;
      Lam[(t * Hn + hh) * LVn + ll] = softplus_f(Lp[hh * LVn + ll] * acc);
    } else {
      const int hh = tid - Hn * LVn;
      const float dtv = softplus_f(acc + dt_bias[hh]);
      g[t * Hn + hh] = -expf(A_log[hh]) * dtv;
    }
  }
}

// ---------------- cumsum of g over t (double precision) ----------------------
__global__ void cumsum_k(const float* __restrict__ g, double* __restrict__ cg) {
  const int h = threadIdx.x;
  if (h < Hn) {
    double a = 0.0;
    for (int t = 0; t < Tn; ++t) {
      a += (double)g[t * Hn + h];
      cg[t * Hn + h] = a;
    }
  }
}

// ---------------- gated causal attention core --------------------------------
__global__ __launch_bounds__(256, 2) void attn_k(
    const float* __restrict__ Q, const float* __restrict__ Km,
    const float* __restrict__ Vm, const double* __restrict__ cg,
    const float* __restrict__ Lam, float* __restrict__ Y) {
  const int h = blockIdx.y;
  const int t0 = blockIdx.x * 64;
  __shared__ float Qs[64][68], Ks[64][68], Vs[64][68], Ps[64][68];
  __shared__ double cgT[64], cgS[64];
  __shared__ float lamT[64][LVn];
  const int tid = threadIdx.x;
  const int tx = tid & 15, ty = tid >> 4;

#pragma unroll
  for (int i = 0; i < 4; ++i) {
    int idx = tid + i * 256;
    int r = idx >> 4, d4 = (idx & 15) * 4;
    *(float4*)&Qs[r][d4] = *(const float4*)&Q[(t0 + r) * Dn + h * Sn + d4];
  }
  if (tid < 64) cgT[tid] = cg[(t0 + tid) * Hn + h];
  for (int i = tid; i < 64 * LVn; i += 256) {
    int r = i / LVn, l = i % LVn;
    lamT[r][l] = Lam[((t0 + r) * Hn + h) * LVn + l];
  }

  float4 accY[4] = {};

  for (int s0 = t0; s0 >= 0; s0 -= 64) {
    __syncthreads();
#pragma unroll
    for (int i = 0; i < 4; ++i) {
      int idx = tid + i * 256;
      int r = idx >> 4, d4 = (idx & 15) * 4;
      *(float4*)&Ks[r][d4] = *(const float4*)&Km[(s0 + r) * Dn + h * Sn + d4];
      *(float4*)&Vs[r][d4] = *(const float4*)&Vm[(s0 + r) * Dn + h * HDn + d4];
    }
    if (tid < 64) cgS[tid] = cg[(s0 + tid) * Hn + h];
    __syncthreads();

    // monotone decay: every remaining tile contributes < e^-80 -> stop
    if (s0 + 64 <= t0 && (float)(cgT[0] - cgS[63]) < -80.f) break;

    // scores: sc[i][j] = Q[t0+ty*4+i] . K[s0+tx*4+j]
    float sc[4][4] = {};
    for (int d = 0; d < 64; d += 4) {
      const float4 a0 = *(const float4*)&Qs[ty * 4 + 0][d];
      const float4 a1 = *(const float4*)&Qs[ty * 4 + 1][d];
      const float4 a2 = *(const float4*)&Qs[ty * 4 + 2][d];
      const float4 a3 = *(const float4*)&Qs[ty * 4 + 3][d];
      const float4 b0 = *(const float4*)&Ks[tx * 4 + 0][d];
      const float4 b1 = *(const float4*)&Ks[tx * 4 + 1][d];
      const float4 b2 = *(const float4*)&Ks[tx * 4 + 2][d];
      const float4 b3 = *(const float4*)&Ks[tx * 4 + 3][d];
      sc[0][0] += a0.x*b0.x + a0.y*b0.y + a0.z*b0.z + a0.w*b0.w;
      sc[0][1] += a0.x*b1.x + a0.y*b1.y + a0.z*b1.z + a0.w*b1.w;
      sc[0][2] += a0.x*b2.x + a0.y*b2.y + a0.z*b2.z + a0.w*b2.w;
      sc[0][3] += a0.x*b3.x + a0.y*b3.y + a0.z*b3.z + a0.w*b3.w;
      sc[1][0] += a1.x*b0.x + a1.y*b0.y + a1.z*b0.z + a1.w*b0.w;
      sc[1][1] += a1.x*b1.x + a1.y*b1.y + a1.z*b1.z + a1.w*b1.w;
      sc[1][2] += a1.x*b2.x + a1.y*b2.y + a1.z*b2.z + a1.w*b2.w;
      sc[1][3] += a1.x*b3.x + a1.y*b3.y + a1.z*b3.z + a1.w*b3.w;
      sc[2][0] += a2.x*b0.x + a2.y*b0.y + a2.z*b0.z + a2.w*b0.w;
      sc[2][1] += a2.x*b1.x + a2.y*b1.y + a2.z*b1.z + a2.w*b1.w;
      sc[2][2] += a2.x*b2.x + a2.y*b2.y + a2.z*b2.z + a2.w*b2.w;
      sc[2][3] += a2.x*b3.x + a2.y*b3.y + a2.z*b3.z + a2.w*b3.w;
      sc[3][0] += a3.x*b0.x + a3.y*b0.y + a3.z*b0.z + a3.w*b0.w;
      sc[3][1] += a3.x*b1.x + a3.y*b1.y + a3.z*b1.z + a3.w*b1.w;
      sc[3][2] += a3.x*b2.x + a3.y*b2.y + a3.z*b2.z + a3.w*b2.w;
      sc[3][3] += a3.x*b3.x + a3.y*b3.y + a3.z*b3.z + a3.w*b3.w;
    }

    // gate: w = sc * S^-0.5 * exp(cg_t - cg_s) * Lam[t,h,level(t,s)], causal
#pragma unroll
    for (int i = 0; i < 4; ++i) {
      const int t = t0 + ty * 4 + i;
      float w[4];
#pragma unroll
      for (int j = 0; j < 4; ++j) {
        const int s = s0 + tx * 4 + j;
        float val = 0.f;
        if (s <= t) {
          const float dd = (float)(cgT[ty * 4 + i] - cgS[tx * 4 + j]);
          const int xr = t ^ s;
          const int lvl = xr ? (32 - __clz(xr)) : 0;
          val = sc[i][j] * 0.125f * expf(dd) * lamT[ty * 4 + i][lvl];
        }
        w[j] = val;
      }
      *(float4*)&Ps[ty * 4 + i][tx * 4] = make_float4(w[0], w[1], w[2], w[3]);
    }
    __syncthreads();

    // PV: accY[i] += sum_ss Ps[ty*4+i][ss] * Vs[ss][tx*4 .. +3]
    for (int ss4 = 0; ss4 < 64; ss4 += 4) {
      const float4 v0 = *(const float4*)&Vs[ss4 + 0][tx * 4];
      const float4 v1 = *(const float4*)&Vs[ss4 + 1][tx * 4];
      const float4 v2 = *(const float4*)&Vs[ss4 + 2][tx * 4];
      const float4 v3 = *(const float4*)&Vs[ss4 + 3][tx * 4];
#pragma unroll
      for (int i = 0; i < 4; ++i) {
        const float4 p = *(const float4*)&Ps[ty * 4 + i][ss4];
        accY[i].x += p.x * v0.x + p.y * v1.x + p.z * v2.x + p.w * v3.x;
        accY[i].y += p.x * v0.y + p.y * v1.y + p.z * v2.y + p.w * v3.y;
        accY[i].z += p.x * v0.z + p.y * v1.z + p.z * v2.z + p.w * v3.z;
        accY[i].w += p.x * v0.w + p.y * v1.w + p.z * v2.w + p.w * v3.w;
      }
    }
  }

#pragma unroll
  for (int i = 0; i < 4; ++i) {
    *(float4*)&Y[(t0 + ty * 4 + i) * Dn + h * HDn + tx * 4] = accY[i];
  }
}

// ---------------- layernorm (in-place on d_out) -------------------------------
__global__ __launch_bounds__(256) void ln_k(float* __restrict__ io,
                                            const float* __restrict__ gw,
                                            const float* __restrict__ bw) {
  const int t = blockIdx.x;
  const int tid = threadIdx.x;
  const float4 v = ((const float4*)(io + t * Dn))[tid];
  float s = v.x + v.y + v.z + v.w;
  float q = v.x * v.x + v.y * v.y + v.z * v.z + v.w * v.w;
#pragma unroll
  for (int off = 32; off >= 1; off >>= 1) {
    s += __shfl_down(s, off);
    q += __shfl_down(q, off);
  }
  __shared__ float sm[4], qm[4];
  const int w = tid >> 6, lane = tid & 63;
  if (lane == 0) { sm[w] = s; qm[w] = q; }
  __syncthreads();
  const float S_ = sm[0] + sm[1] + sm[2] + sm[3];
  const float Q_ = qm[0] + qm[1] + qm[2] + qm[3];
  const float mu = S_ * (1.f / Dn);
  const float var = Q_ * (1.f / Dn) - mu * mu;
  const float inv = rsqrtf(var + 1e-5f);
  const float4 gg = ((const float4*)gw)[tid];
  const float4 bb = ((const float4*)bw)[tid];
  float4 o;
  o.x = (v.x - mu) * inv * gg.x + bb.x;
  o.y = (v.y - mu) * inv * gg.y + bb.y;
  o.z = (v.z - mu) * inv * gg.z + bb.z;
  o.w = (v.w - mu) * inv * gg.w + bb.w;
  ((float4*)(io + t * Dn))[tid] = o;
}

extern "C" void kernel_launch(void* const* d_in, const int* in_sizes, int n_in,
                              void* d_out, int out_size, void* d_ws, size_t ws_size,
                              hipStream_t stream) {
  (void)in_sizes; (void)n_in; (void)out_size; (void)ws_size;
  const float* x      = (const float*)d_in[0];
  const float* Wq     = (const float*)d_in[1];
  const float* Wk     = (const float*)d_in[2];
  const float* Wv     = (const float*)d_in[3];
  const float* Wdl    = (const float*)d_in[4];
  const float* Wdt    = (const float*)d_in[5];
  const float* Wout   = (const float*)d_in[6];
  const float* A_log  = (const float*)d_in[7];
  const float* dt_bias= (const float*)d_in[8];
  const float* Lp     = (const float*)d_in[9];
  const float* ln_g   = (const float*)d_in[10];
  const float* ln_b   = (const float*)d_in[11];
  float* out = (float*)d_out;
  float* ws  = (float*)d_ws;

  const size_t MAT = (size_t)Tn * Dn;   // 2,097,152
  const size_t WSZ = (size_t)Dn * Dn;   // 1,048,576
  size_t off = 0;
  float*  Qb   = ws + off; off += MAT;
  float*  Kb   = ws + off; off += MAT;
  float*  Vb   = ws + off; off += MAT;
  float*  Yb   = ws + off; off += MAT;
  float*  gb   = ws + off; off += (size_t)Tn * Hn;
  double* cgd  = (double*)(ws + off); off += 2 * (size_t)Tn * Hn;
  float*  Lamb = ws + off; off += (size_t)Tn * Hn * LVn;
  unsigned short* xb16 = (unsigned short*)(ws + off); off += MAT / 2;
  unsigned short* Wq16 = (unsigned short*)(ws + off); off += WSZ / 2;
  unsigned short* Wk16 = (unsigned short*)(ws + off); off += WSZ / 2;
  unsigned short* Wv16 = (unsigned short*)(ws + off); off += WSZ / 2;
  unsigned short* Wo16 = (unsigned short*)(ws + off); off += WSZ / 2;
  unsigned short* Y16  = (unsigned short*)(ws + off); off += MAT / 2;

  // 1. convert x (2M elems) + 4 weight matrices (1M each) to bf16
  cvt1_k<<<dim3(MAT / (256 * 8)), 256, 0, stream>>>(x, xb16);
  cvt5_k<<<dim3(WSZ / (256 * 8), 5), 256, 0, stream>>>(
      Wq, Wq16, Wk, Wk16, Wv, Wv16, Wout, Wo16, Wq, Wq16);
  // 2. Q/K/V projections (bf16 MFMA)
  mfma_gemm_k<<<dim3(Tn / 128, Dn / 128, 3), 256, 0, stream>>>(
      xb16, Wq16, Wk16, Wv16, nullptr, Qb, Kb, Vb);
  // 3. small projections + cumsum
  proj_small_k<<<dim3(Tn), 256, 0, stream>>>(x, Wdl, Wdt, A_log, dt_bias, Lp, Lamb, gb);
  cumsum_k<<<1, 64, 0, stream>>>(gb, cgd);
  // 4. attention core (fp32)
  attn_k<<<dim3(Tn / 64, Hn), 256, 0, stream>>>(Qb, Kb, Vb, cgd, Lamb, Yb);
  // 5. Y -> bf16, out-proj + residual (bf16 MFMA), layernorm
  cvt1_k<<<dim3(MAT / (256 * 8)), 256, 0, stream>>>(Yb, Y16);
  mfma_gemm_k<<<dim3(Tn / 128, Dn / 128, 1), 256, 0, stream>>>(
      Y16, Wo16, nullptr, nullptr, x, out, nullptr, nullptr);
  ln_k<<<dim3(Tn), 256, 0, stream>>>(out, ln_g, ln_b);
}

// Round 5
// 183.839 us; speedup vs baseline: 4.9809x; 2.2427x over previous
//
#include <hip/hip_runtime.h>
#include <math.h>

#define Tn 2048
#define Dn 1024
#define Hn 16
#define Sn 64
#define LVn 12
#define HDn 64

typedef short short8 __attribute__((ext_vector_type(8)));
typedef unsigned short ushortv8 __attribute__((ext_vector_type(8)));
typedef float floatx4 __attribute__((ext_vector_type(4)));

__device__ __forceinline__ float softplus_f(float z) {
  return (z > 0.f) ? (z + log1pf(expf(-z))) : log1pf(expf(z));
}

__device__ __forceinline__ unsigned short f2bf(float f) {
  union { float f; unsigned u; } v; v.f = f;
  unsigned r = v.u + 0x7FFF + ((v.u >> 16) & 1);  // RNE
  return (unsigned short)(r >> 16);
}

__device__ __forceinline__ void gld16(const void* g, void* l) {
  __builtin_amdgcn_global_load_lds(
      (const __attribute__((address_space(1))) unsigned int*)g,
      (__attribute__((address_space(3))) unsigned int*)l, 16, 0, 0);
}

// ---------------- fp32 -> bf16 conversions ------------------------------------
__global__ __launch_bounds__(256) void cvt4_k(
    const float* __restrict__ w0, unsigned short* __restrict__ w0b,
    const float* __restrict__ w1, unsigned short* __restrict__ w1b,
    const float* __restrict__ w2, unsigned short* __restrict__ w2b,
    const float* __restrict__ w3, unsigned short* __restrict__ w3b) {
  const int seg = blockIdx.y;
  const float* s; unsigned short* d;
  if (seg == 0)      { s = w0; d = w0b; }
  else if (seg == 1) { s = w1; d = w1b; }
  else if (seg == 2) { s = w2; d = w2b; }
  else               { s = w3; d = w3b; }
  const int i = (blockIdx.x * 256 + threadIdx.x) * 8;
  const float4 u0 = *(const float4*)&s[i];
  const float4 u1 = *(const float4*)&s[i + 4];
  ushortv8 o;
  o[0] = f2bf(u0.x); o[1] = f2bf(u0.y); o[2] = f2bf(u0.z); o[3] = f2bf(u0.w);
  o[4] = f2bf(u1.x); o[5] = f2bf(u1.y); o[6] = f2bf(u1.z); o[7] = f2bf(u1.w);
  *(ushortv8*)&d[i] = o;
}

__global__ __launch_bounds__(256) void cvt1_k(const float* __restrict__ s,
                                              unsigned short* __restrict__ d) {
  const int i = (blockIdx.x * 256 + threadIdx.x) * 8;
  const float4 u0 = *(const float4*)&s[i];
  const float4 u1 = *(const float4*)&s[i + 4];
  ushortv8 o;
  o[0] = f2bf(u0.x); o[1] = f2bf(u0.y); o[2] = f2bf(u0.z); o[3] = f2bf(u0.w);
  o[4] = f2bf(u1.x); o[5] = f2bf(u1.y); o[6] = f2bf(u1.z); o[7] = f2bf(u1.w);
  *(ushortv8*)&d[i] = o;
}

// Wdl [192][1024] -> bf16 padded to [256][1024] (rows 192..255 zero)
__global__ __launch_bounds__(256) void cvt_wsmall_k(const float* __restrict__ s,
                                                    unsigned short* __restrict__ d) {
  const int i = (blockIdx.x * 256 + threadIdx.x) * 8;  // into 256*1024
  const int row = i >> 10;
  ushortv8 o;
  if (row < Hn * LVn) {
    const float4 u0 = *(const float4*)&s[i];
    const float4 u1 = *(const float4*)&s[i + 4];
    o[0] = f2bf(u0.x); o[1] = f2bf(u0.y); o[2] = f2bf(u0.z); o[3] = f2bf(u0.w);
    o[4] = f2bf(u1.x); o[5] = f2bf(u1.y); o[6] = f2bf(u1.z); o[7] = f2bf(u1.w);
  } else {
    o = (ushortv8)0;
  }
  *(ushortv8*)&d[i] = o;
}

// ---------------- bf16 MFMA GEMM: C[m][n] = sum_k A[m][k]*B[n][k] (+R) -------
// 128x128 tile, BK=32, 256 threads = 4 waves (2x2), 16x16x32 bf16 MFMA.
// A stride = Dn (K=1024). C/R stride = ldc.
__global__ __launch_bounds__(256) void mfma_gemm_k(
    const unsigned short* __restrict__ A,
    const unsigned short* __restrict__ B0, const unsigned short* __restrict__ B1,
    const unsigned short* __restrict__ B2,
    const float* __restrict__ R,
    float* __restrict__ C0, float* __restrict__ C1, float* __restrict__ C2,
    int ldc) {
  const unsigned short* B = blockIdx.z == 0 ? B0 : blockIdx.z == 1 ? B1 : B2;
  float* C = blockIdx.z == 0 ? C0 : blockIdx.z == 1 ? C1 : C2;
  __shared__ unsigned short lA[128 * 32];
  __shared__ unsigned short lB[128 * 32];
  const int tid = threadIdx.x;
  const int bm = blockIdx.x * 128, bn = blockIdx.y * 128;
  const int lane = tid & 63, wave = tid >> 6;
  const int wm = wave >> 1, wn = wave & 1;
  const int l16 = lane & 15, lk = lane >> 4;
  const int sr = tid >> 2, sc = (tid & 3) * 8;  // staging row/col
  floatx4 acc[4][4] = {};
  for (int k0 = 0; k0 < Dn; k0 += 32) {
    __syncthreads();
    gld16(&A[(size_t)(bm + sr) * Dn + k0 + sc],      &lA[tid * 8]);
    gld16(&A[(size_t)(bm + 64 + sr) * Dn + k0 + sc], &lA[2048 + tid * 8]);
    gld16(&B[(size_t)(bn + sr) * Dn + k0 + sc],      &lB[tid * 8]);
    gld16(&B[(size_t)(bn + 64 + sr) * Dn + k0 + sc], &lB[2048 + tid * 8]);
    __syncthreads();
    short8 a[4], b[4];
#pragma unroll
    for (int mf = 0; mf < 4; ++mf)
      a[mf] = *(const short8*)&lA[(wm * 64 + mf * 16 + l16) * 32 + lk * 8];
#pragma unroll
    for (int nf = 0; nf < 4; ++nf)
      b[nf] = *(const short8*)&lB[(wn * 64 + nf * 16 + l16) * 32 + lk * 8];
#pragma unroll
    for (int mf = 0; mf < 4; ++mf)
#pragma unroll
      for (int nf = 0; nf < 4; ++nf)
        acc[mf][nf] = __builtin_amdgcn_mfma_f32_16x16x32_bf16(
            a[mf], b[nf], acc[mf][nf], 0, 0, 0);
  }
#pragma unroll
  for (int mf = 0; mf < 4; ++mf) {
#pragma unroll
    for (int nf = 0; nf < 4; ++nf) {
      const int col = bn + wn * 64 + nf * 16 + l16;
#pragma unroll
      for (int r = 0; r < 4; ++r) {
        const int row = bm + wm * 64 + mf * 16 + lk * 4 + r;
        float v = acc[mf][nf][r];
        if (R) v += R[(size_t)row * ldc + col];
        C[(size_t)row * ldc + col] = v;
      }
    }
  }
}

// ---------------- dt projection (fp32, precision-critical) -------------------
// g[t,h] = -exp(A_log[h]) * softplus(x[t] . Wdt[h] + dt_bias[h])
__global__ __launch_bounds__(256) void dt_k(
    const float* __restrict__ x, const float* __restrict__ Wdt,
    const float* __restrict__ A_log, const float* __restrict__ dt_bias,
    float* __restrict__ g) {
  const int t0 = blockIdx.x * 8;
  __shared__ float xs[8][Dn];
  const int tid = threadIdx.x;
#pragma unroll
  for (int i = 0; i < 8; ++i)
    ((float4*)xs[i])[tid] = ((const float4*)&x[(size_t)(t0 + i) * Dn])[tid];
  __syncthreads();
  const int d = tid >> 1, half = tid & 1;
  const int tl = d >> 4, h = d & 15;
  const float4* xr = (const float4*)&xs[tl][half * 512];
  const float4* wr = (const float4*)&Wdt[h * Dn + half * 512];
  float acc = 0.f;
#pragma unroll 4
  for (int k = 0; k < 128; ++k) {
    const float4 a = xr[k], b = wr[k];
    acc += a.x * b.x + a.y * b.y + a.z * b.z + a.w * b.w;
  }
  acc += __shfl_xor(acc, 1);
  if (half == 0) {
    const float dtv = softplus_f(acc + dt_bias[h]);
    g[(t0 + tl) * Hn + h] = -expf(A_log[h]) * dtv;
  }
}

// ---------------- per-head parallel cumsum (double) --------------------------
__global__ __launch_bounds__(256) void scan_k(const float* __restrict__ g,
                                              double* __restrict__ cg) {
  const int h = blockIdx.x;
  const int tid = threadIdx.x;
  double v[8];
  double run = 0.0;
#pragma unroll
  for (int i = 0; i < 8; ++i) {
    run += (double)g[(tid * 8 + i) * Hn + h];
    v[i] = run;
  }
  __shared__ double ls[256];
  ls[tid] = run;
  __syncthreads();
  for (int off = 1; off < 256; off <<= 1) {
    double add = (tid >= off) ? ls[tid - off] : 0.0;
    __syncthreads();
    ls[tid] += add;
    __syncthreads();
  }
  const double excl = ls[tid] - run;
#pragma unroll
  for (int i = 0; i < 8; ++i) cg[(tid * 8 + i) * Hn + h] = excl + v[i];
}

// ---------------- gated causal attention core --------------------------------
__global__ __launch_bounds__(256, 2) void attn_k(
    const float* __restrict__ Q, const float* __restrict__ Km,
    const float* __restrict__ Vm, const double* __restrict__ cg,
    const float* __restrict__ dlb, const float* __restrict__ Lp,
    float* __restrict__ Y) {
  const int h = blockIdx.y;
  const int t0 = blockIdx.x * 64;
  __shared__ float Qs[64][68], Ks[64][68], Vs[64][68], Ps[64][68];
  __shared__ double cgT[64], cgS[64];
  __shared__ float lamT[64][LVn];
  const int tid = threadIdx.x;
  const int tx = tid & 15, ty = tid >> 4;

#pragma unroll
  for (int i = 0; i < 4; ++i) {
    int idx = tid + i * 256;
    int r = idx >> 4, d4 = (idx & 15) * 4;
    *(float4*)&Qs[r][d4] = *(const float4*)&Q[(t0 + r) * Dn + h * Sn + d4];
  }
  if (tid < 64) cgT[tid] = cg[(t0 + tid) * Hn + h];
  for (int i = tid; i < 64 * LVn; i += 256) {
    int r = i / LVn, l = i % LVn;
    lamT[r][l] = softplus_f(Lp[h * LVn + l] * dlb[(size_t)(t0 + r) * 256 + h * LVn + l]);
  }

  float4 accY[4] = {};

  for (int s0 = t0; s0 >= 0; s0 -= 64) {
    __syncthreads();
#pragma unroll
    for (int i = 0; i < 4; ++i) {
      int idx = tid + i * 256;
      int r = idx >> 4, d4 = (idx & 15) * 4;
      *(float4*)&Ks[r][d4] = *(const float4*)&Km[(s0 + r) * Dn + h * Sn + d4];
      *(float4*)&Vs[r][d4] = *(const float4*)&Vm[(s0 + r) * Dn + h * HDn + d4];
    }
    if (tid < 64) cgS[tid] = cg[(s0 + tid) * Hn + h];
    __syncthreads();

    // monotone decay: every remaining tile contributes < e^-80 -> stop
    if (s0 + 64 <= t0 && (float)(cgT[0] - cgS[63]) < -80.f) break;

    float sc[4][4] = {};
    for (int dd = 0; dd < 64; dd += 4) {
      const float4 a0 = *(const float4*)&Qs[ty * 4 + 0][dd];
      const float4 a1 = *(const float4*)&Qs[ty * 4 + 1][dd];
      const float4 a2 = *(const float4*)&Qs[ty * 4 + 2][dd];
      const float4 a3 = *(const float4*)&Qs[ty * 4 + 3][dd];
      const float4 b0 = *(const float4*)&Ks[tx * 4 + 0][dd];
      const float4 b1 = *(const float4*)&Ks[tx * 4 + 1][dd];
      const float4 b2 = *(const float4*)&Ks[tx * 4 + 2][dd];
      const float4 b3 = *(const float4*)&Ks[tx * 4 + 3][dd];
      sc[0][0] += a0.x*b0.x + a0.y*b0.y + a0.z*b0.z + a0.w*b0.w;
      sc[0][1] += a0.x*b1.x + a0.y*b1.y + a0.z*b1.z + a0.w*b1.w;
      sc[0][2] += a0.x*b2.x + a0.y*b2.y + a0.z*b2.z + a0.w*b2.w;
      sc[0][3] += a0.x*b3.x + a0.y*b3.y + a0.z*b3.z + a0.w*b3.w;
      sc[1][0] += a1.x*b0.x + a1.y*b0.y + a1.z*b0.z + a1.w*b0.w;
      sc[1][1] += a1.x*b1.x + a1.y*b1.y + a1.z*b1.z + a1.w*b1.w;
      sc[1][2] += a1.x*b2.x + a1.y*b2.y + a1.z*b2.z + a1.w*b2.w;
      sc[1][3] += a1.x*b3.x + a1.y*b3.y + a1.z*b3.z + a1.w*b3.w;
      sc[2][0] += a2.x*b0.x + a2.y*b0.y + a2.z*b0.z + a2.w*b0.w;
      sc[2][1] += a2.x*b1.x + a2.y*b1.y + a2.z*b1.z + a2.w*b1.w;
      sc[2][2] += a2.x*b2.x + a2.y*b2.y + a2.z*b2.z + a2.w*b2.w;
      sc[2][3] += a2.x*b3.x + a2.y*b3.y + a2.z*b3.z + a2.w*b3.w;
      sc[3][0] += a3.x*b0.x + a3.y*b0.y + a3.z*b0.z + a3.w*b0.w;
      sc[3][1] += a3.x*b1.x + a3.y*b1.y + a3.z*b1.z + a3.w*b1.w;
      sc[3][2] += a3.x*b2.x + a3.y*b2.y + a3.z*b2.z + a3.w*b2.w;
      sc[3][3] += a3.x*b3.x + a3.y*b3.y + a3.z*b3.z + a3.w*b3.w;
    }

#pragma unroll
    for (int i = 0; i < 4; ++i) {
      const int t = t0 + ty * 4 + i;
      float w[4];
#pragma unroll
      for (int j = 0; j < 4; ++j) {
        const int s = s0 + tx * 4 + j;
        float val = 0.f;
        if (s <= t) {
          const float dd = (float)(cgT[ty * 4 + i] - cgS[tx * 4 + j]);
          const int xr = t ^ s;
          const int lvl = xr ? (32 - __clz(xr)) : 0;
          val = sc[i][j] * 0.125f * expf(dd) * lamT[ty * 4 + i][lvl];
        }
        w[j] = val;
      }
      *(float4*)&Ps[ty * 4 + i][tx * 4] = make_float4(w[0], w[1], w[2], w[3]);
    }
    __syncthreads();

    for (int ss4 = 0; ss4 < 64; ss4 += 4) {
      const float4 v0 = *(const float4*)&Vs[ss4 + 0][tx * 4];
      const float4 v1 = *(const float4*)&Vs[ss4 + 1][tx * 4];
      const float4 v2 = *(const float4*)&Vs[ss4 + 2][tx * 4];
      const float4 v3 = *(const float4*)&Vs[ss4 + 3][tx * 4];
#pragma unroll
      for (int i = 0; i < 4; ++i) {
        const float4 p = *(const float4*)&Ps[ty * 4 + i][ss4];
        accY[i].x += p.x * v0.x + p.y * v1.x + p.z * v2.x + p.w * v3.x;
        accY[i].y += p.x * v0.y + p.y * v1.y + p.z * v2.y + p.w * v3.y;
        accY[i].z += p.x * v0.z + p.y * v1.z + p.z * v2.z + p.w * v3.z;
        accY[i].w += p.x * v0.w + p.y * v1.w + p.z * v2.w + p.w * v3.w;
      }
    }
  }

#pragma unroll
  for (int i = 0; i < 4; ++i) {
    *(float4*)&Y[(t0 + ty * 4 + i) * Dn + h * HDn + tx * 4] = accY[i];
  }
}

// ---------------- layernorm (in-place on d_out) -------------------------------
__global__ __launch_bounds__(256) void ln_k(float* __restrict__ io,
                                            const float* __restrict__ gw,
                                            const float* __restrict__ bw) {
  const int t = blockIdx.x;
  const int tid = threadIdx.x;
  const float4 v = ((const float4*)(io + t * Dn))[tid];
  float s = v.x + v.y + v.z + v.w;
  float q = v.x * v.x + v.y * v.y + v.z * v.z + v.w * v.w;
#pragma unroll
  for (int off = 32; off >= 1; off >>= 1) {
    s += __shfl_down(s, off);
    q += __shfl_down(q, off);
  }
  __shared__ float sm[4], qm[4];
  const int w = tid >> 6, lane = tid & 63;
  if (lane == 0) { sm[w] = s; qm[w] = q; }
  __syncthreads();
  const float S_ = sm[0] + sm[1] + sm[2] + sm[3];
  const float Q_ = qm[0] + qm[1] + qm[2] + qm[3];
  const float mu = S_ * (1.f / Dn);
  const float var = Q_ * (1.f / Dn) - mu * mu;
  const float inv = rsqrtf(var + 1e-5f);
  const float4 gg = ((const float4*)gw)[tid];
  const float4 bb = ((const float4*)bw)[tid];
  float4 o;
  o.x = (v.x - mu) * inv * gg.x + bb.x;
  o.y = (v.y - mu) * inv * gg.y + bb.y;
  o.z = (v.z - mu) * inv * gg.z + bb.z;
  o.w = (v.w - mu) * inv * gg.w + bb.w;
  ((float4*)(io + t * Dn))[tid] = o;
}

extern "C" void kernel_launch(void* const* d_in, const int* in_sizes, int n_in,
                              void* d_out, int out_size, void* d_ws, size_t ws_size,
                              hipStream_t stream) {
  (void)in_sizes; (void)n_in; (void)out_size; (void)ws_size;
  const float* x      = (const float*)d_in[0];
  const float* Wq     = (const float*)d_in[1];
  const float* Wk     = (const float*)d_in[2];
  const float* Wv     = (const float*)d_in[3];
  const float* Wdl    = (const float*)d_in[4];
  const float* Wdt    = (const float*)d_in[5];
  const float* Wout   = (const float*)d_in[6];
  const float* A_log  = (const float*)d_in[7];
  const float* dt_bias= (const float*)d_in[8];
  const float* Lp     = (const float*)d_in[9];
  const float* ln_g   = (const float*)d_in[10];
  const float* ln_b   = (const float*)d_in[11];
  float* out = (float*)d_out;
  float* ws  = (float*)d_ws;

  const size_t MAT = (size_t)Tn * Dn;   // 2,097,152
  const size_t WSZ = (size_t)Dn * Dn;   // 1,048,576
  size_t off = 0;
  float*  Qb   = ws + off; off += MAT;
  float*  Kb   = ws + off; off += MAT;
  float*  Vb   = ws + off; off += MAT;
  float*  Yb   = ws + off; off += MAT;
  float*  gb   = ws + off; off += (size_t)Tn * Hn;
  double* cgd  = (double*)(ws + off); off += 2 * (size_t)Tn * Hn;
  float*  dlb  = ws + off; off += (size_t)Tn * 256;
  unsigned short* xb16 = (unsigned short*)(ws + off); off += MAT / 2;
  unsigned short* Wq16 = (unsigned short*)(ws + off); off += WSZ / 2;
  unsigned short* Wk16 = (unsigned short*)(ws + off); off += WSZ / 2;
  unsigned short* Wv16 = (unsigned short*)(ws + off); off += WSZ / 2;
  unsigned short* Wo16 = (unsigned short*)(ws + off); off += WSZ / 2;
  unsigned short* Ws16 = (unsigned short*)(ws + off); off += (size_t)256 * Dn / 2;
  unsigned short* Y16  = xb16;  // alias: xb16 dead after QKV+dl GEMMs

  // 1. bf16 conversions
  cvt1_k<<<dim3(MAT / 2048), 256, 0, stream>>>(x, xb16);
  cvt4_k<<<dim3(WSZ / 2048, 4), 256, 0, stream>>>(
      Wq, Wq16, Wk, Wk16, Wv, Wv16, Wout, Wo16);
  cvt_wsmall_k<<<dim3(256 * Dn / 2048), 256, 0, stream>>>(Wdl, Ws16);
  // 2. Q/K/V projections (bf16 MFMA)
  mfma_gemm_k<<<dim3(Tn / 128, Dn / 128, 3), 256, 0, stream>>>(
      xb16, Wq16, Wk16, Wv16, nullptr, Qb, Kb, Vb, Dn);
  // 3. dl projection (bf16 MFMA, N=256 padded)
  mfma_gemm_k<<<dim3(Tn / 128, 2, 1), 256, 0, stream>>>(
      xb16, Ws16, nullptr, nullptr, nullptr, dlb, nullptr, nullptr, 256);
  // 4. dt projection (fp32) + per-head cumsum
  dt_k<<<dim3(Tn / 8), 256, 0, stream>>>(x, Wdt, A_log, dt_bias, gb);
  scan_k<<<dim3(Hn), 256, 0, stream>>>(gb, cgd);
  // 5. attention core (fp32)
  attn_k<<<dim3(Tn / 64, Hn), 256, 0, stream>>>(Qb, Kb, Vb, cgd, dlb, Lp, Yb);
  // 6. Y -> bf16, out-proj + residual (bf16 MFMA), layernorm
  cvt1_k<<<dim3(MAT / 2048), 256, 0, stream>>>(Yb, Y16);
  mfma_gemm_k<<<dim3(Tn / 128, Dn / 128, 1), 256, 0, stream>>>(
      Y16, Wo16, nullptr, nullptr, x, out, nullptr, nullptr, Dn);
  ln_k<<<dim3(Tn), 256, 0, stream>>>(out, ln_g, ln_b);
}

// Round 6
// 149.027 us; speedup vs baseline: 6.1444x; 1.2336x over previous
//
#include <hip/hip_runtime.h>
#include <math.h>

#define Tn 2048
#define Dn 1024
#define Hn 16
#define Sn 64
#define LVn 12
#define HDn 64

typedef short short8 __attribute__((ext_vector_type(8)));
typedef unsigned short ushortv8 __attribute__((ext_vector_type(8)));
typedef float floatx4 __attribute__((ext_vector_type(4)));

__device__ __forceinline__ float softplus_f(float z) {
  return (z > 0.f) ? (z + log1pf(expf(-z))) : log1pf(expf(z));
}

__device__ __forceinline__ unsigned short f2bf(float f) {
  union { float f; unsigned u; } v; v.f = f;
  unsigned r = v.u + 0x7FFF + ((v.u >> 16) & 1);  // RNE
  return (unsigned short)(r >> 16);
}

__device__ __forceinline__ void gld16(const void* g, void* l) {
  __builtin_amdgcn_global_load_lds(
      (const __attribute__((address_space(1))) unsigned int*)g,
      (__attribute__((address_space(3))) unsigned int*)l, 16, 0, 0);
}

// ---------------- fp32 -> bf16 conversions ------------------------------------
__global__ __launch_bounds__(256) void cvt4_k(
    const float* __restrict__ w0, unsigned short* __restrict__ w0b,
    const float* __restrict__ w1, unsigned short* __restrict__ w1b,
    const float* __restrict__ w2, unsigned short* __restrict__ w2b,
    const float* __restrict__ w3, unsigned short* __restrict__ w3b) {
  const int seg = blockIdx.y;
  const float* s; unsigned short* d;
  if (seg == 0)      { s = w0; d = w0b; }
  else if (seg == 1) { s = w1; d = w1b; }
  else if (seg == 2) { s = w2; d = w2b; }
  else               { s = w3; d = w3b; }
  const int i = (blockIdx.x * 256 + threadIdx.x) * 8;
  const float4 u0 = *(const float4*)&s[i];
  const float4 u1 = *(const float4*)&s[i + 4];
  ushortv8 o;
  o[0] = f2bf(u0.x); o[1] = f2bf(u0.y); o[2] = f2bf(u0.z); o[3] = f2bf(u0.w);
  o[4] = f2bf(u1.x); o[5] = f2bf(u1.y); o[6] = f2bf(u1.z); o[7] = f2bf(u1.w);
  *(ushortv8*)&d[i] = o;
}

__global__ __launch_bounds__(256) void cvt1_k(const float* __restrict__ s,
                                              unsigned short* __restrict__ d) {
  const int i = (blockIdx.x * 256 + threadIdx.x) * 8;
  const float4 u0 = *(const float4*)&s[i];
  const float4 u1 = *(const float4*)&s[i + 4];
  ushortv8 o;
  o[0] = f2bf(u0.x); o[1] = f2bf(u0.y); o[2] = f2bf(u0.z); o[3] = f2bf(u0.w);
  o[4] = f2bf(u1.x); o[5] = f2bf(u1.y); o[6] = f2bf(u1.z); o[7] = f2bf(u1.w);
  *(ushortv8*)&d[i] = o;
}

// Wdl [192][1024] -> bf16 padded to [256][1024] (rows 192..255 zero)
__global__ __launch_bounds__(256) void cvt_wsmall_k(const float* __restrict__ s,
                                                    unsigned short* __restrict__ d) {
  const int i = (blockIdx.x * 256 + threadIdx.x) * 8;
  const int row = i >> 10;
  ushortv8 o;
  if (row < Hn * LVn) {
    const float4 u0 = *(const float4*)&s[i];
    const float4 u1 = *(const float4*)&s[i + 4];
    o[0] = f2bf(u0.x); o[1] = f2bf(u0.y); o[2] = f2bf(u0.z); o[3] = f2bf(u0.w);
    o[4] = f2bf(u1.x); o[5] = f2bf(u1.y); o[6] = f2bf(u1.z); o[7] = f2bf(u1.w);
  } else {
    o = (ushortv8)0;
  }
  *(ushortv8*)&d[i] = o;
}

// ---------------- bf16 MFMA GEMM: C[m][n] = sum_k A[m][k]*B[n][k] (+R) -------
// 128x128 tile, BK=32, 256 threads = 4 waves (2x2), 16x16x32 bf16 MFMA.
// obf16: write C as bf16 (ushort), else fp32.
__global__ __launch_bounds__(256) void mfma_gemm_k(
    const unsigned short* __restrict__ A,
    const unsigned short* __restrict__ B0, const unsigned short* __restrict__ B1,
    const unsigned short* __restrict__ B2,
    const float* __restrict__ R,
    float* __restrict__ C0, float* __restrict__ C1, float* __restrict__ C2,
    int ldc, int obf16) {
  const unsigned short* B = blockIdx.z == 0 ? B0 : blockIdx.z == 1 ? B1 : B2;
  float* C = blockIdx.z == 0 ? C0 : blockIdx.z == 1 ? C1 : C2;
  __shared__ unsigned short lA[128 * 32];
  __shared__ unsigned short lB[128 * 32];
  const int tid = threadIdx.x;
  const int bm = blockIdx.x * 128, bn = blockIdx.y * 128;
  const int lane = tid & 63, wave = tid >> 6;
  const int wm = wave >> 1, wn = wave & 1;
  const int l16 = lane & 15, lk = lane >> 4;
  const int sr = tid >> 2, sc = (tid & 3) * 8;
  floatx4 acc[4][4] = {};
  for (int k0 = 0; k0 < Dn; k0 += 32) {
    __syncthreads();
    gld16(&A[(size_t)(bm + sr) * Dn + k0 + sc],      &lA[tid * 8]);
    gld16(&A[(size_t)(bm + 64 + sr) * Dn + k0 + sc], &lA[2048 + tid * 8]);
    gld16(&B[(size_t)(bn + sr) * Dn + k0 + sc],      &lB[tid * 8]);
    gld16(&B[(size_t)(bn + 64 + sr) * Dn + k0 + sc], &lB[2048 + tid * 8]);
    __syncthreads();
    short8 a[4], b[4];
#pragma unroll
    for (int mf = 0; mf < 4; ++mf)
      a[mf] = *(const short8*)&lA[(wm * 64 + mf * 16 + l16) * 32 + lk * 8];
#pragma unroll
    for (int nf = 0; nf < 4; ++nf)
      b[nf] = *(const short8*)&lB[(wn * 64 + nf * 16 + l16) * 32 + lk * 8];
#pragma unroll
    for (int mf = 0; mf < 4; ++mf)
#pragma unroll
      for (int nf = 0; nf < 4; ++nf)
        acc[mf][nf] = __builtin_amdgcn_mfma_f32_16x16x32_bf16(
            a[mf], b[nf], acc[mf][nf], 0, 0, 0);
  }
#pragma unroll
  for (int mf = 0; mf < 4; ++mf) {
#pragma unroll
    for (int nf = 0; nf < 4; ++nf) {
      const int col = bn + wn * 64 + nf * 16 + l16;
#pragma unroll
      for (int r = 0; r < 4; ++r) {
        const int row = bm + wm * 64 + mf * 16 + lk * 4 + r;
        float v = acc[mf][nf][r];
        if (R) v += R[(size_t)row * ldc + col];
        if (obf16) ((unsigned short*)C)[(size_t)row * ldc + col] = f2bf(v);
        else       C[(size_t)row * ldc + col] = v;
      }
    }
  }
}

// ---------------- dt projection (fp32, precision-critical) -------------------
__global__ __launch_bounds__(256) void dt_k(
    const float* __restrict__ x, const float* __restrict__ Wdt,
    const float* __restrict__ A_log, const float* __restrict__ dt_bias,
    float* __restrict__ g) {
  const int t0 = blockIdx.x * 8;
  __shared__ float xs[8][Dn];
  const int tid = threadIdx.x;
#pragma unroll
  for (int i = 0; i < 8; ++i)
    ((float4*)xs[i])[tid] = ((const float4*)&x[(size_t)(t0 + i) * Dn])[tid];
  __syncthreads();
  const int d = tid >> 1, half = tid & 1;
  const int tl = d >> 4, h = d & 15;
  const float4* xr = (const float4*)&xs[tl][half * 512];
  const float4* wr = (const float4*)&Wdt[h * Dn + half * 512];
  float acc = 0.f;
#pragma unroll 4
  for (int k = 0; k < 128; ++k) {
    const float4 a = xr[k], b = wr[k];
    acc += a.x * b.x + a.y * b.y + a.z * b.z + a.w * b.w;
  }
  acc += __shfl_xor(acc, 1);
  if (half == 0) {
    const float dtv = softplus_f(acc + dt_bias[h]);
    g[(t0 + tl) * Hn + h] = -expf(A_log[h]) * dtv;
  }
}

// ---------------- per-head parallel cumsum (double) --------------------------
__global__ __launch_bounds__(256) void scan_k(const float* __restrict__ g,
                                              double* __restrict__ cg) {
  const int h = blockIdx.x;
  const int tid = threadIdx.x;
  double v[8];
  double run = 0.0;
#pragma unroll
  for (int i = 0; i < 8; ++i) {
    run += (double)g[(tid * 8 + i) * Hn + h];
    v[i] = run;
  }
  __shared__ double ls[256];
  ls[tid] = run;
  __syncthreads();
  for (int off = 1; off < 256; off <<= 1) {
    double add = (tid >= off) ? ls[tid - off] : 0.0;
    __syncthreads();
    ls[tid] += add;
    __syncthreads();
  }
  const double excl = ls[tid] - run;
#pragma unroll
  for (int i = 0; i < 8; ++i) cg[(tid * 8 + i) * Hn + h] = excl + v[i];
}

// ---------------- gated causal attention core (bf16 MFMA) --------------------
// Q,K,V,Y bf16 [2048][1024]. 64x64 t/s tiles, 4 waves (2x2).
__global__ __launch_bounds__(256) void attn_k(
    const unsigned short* __restrict__ Q, const unsigned short* __restrict__ K,
    const unsigned short* __restrict__ V, const double* __restrict__ cg,
    const float* __restrict__ dlb, const float* __restrict__ Lp,
    unsigned short* __restrict__ Y) {
  const int h = blockIdx.y;
  const int t0 = blockIdx.x * 64;
  __shared__ unsigned short Qs[64][72], Ks[64][72], Ps[64][72], Vt[64][72];
  __shared__ float cgT[64], cgS[64];
  __shared__ float lamT[64][LVn];
  const int tid = threadIdx.x;
  const int lane = tid & 63, wave = tid >> 6;
  const int wm = wave >> 1, wn = wave & 1;
  const int l16 = lane & 15, lk = lane >> 4;

  // stage Q (bf16): chunk c -> row c>>3, col8 (c&7)*8
#pragma unroll
  for (int p = 0; p < 2; ++p) {
    const int c = tid + p * 256, r = c >> 3, c8 = (c & 7) * 8;
    *(ushortv8*)&Qs[r][c8] = *(const ushortv8*)&Q[(size_t)(t0 + r) * Dn + h * Sn + c8];
  }
  if (tid < 64) cgT[tid] = (float)cg[(t0 + tid) * Hn + h];
  for (int i = tid; i < 64 * LVn; i += 256) {
    const int r = i / LVn, l = i % LVn;
    lamT[r][l] = softplus_f(Lp[h * LVn + l] * dlb[(size_t)(t0 + r) * 256 + h * LVn + l]);
  }

  floatx4 accY[2][2] = {};

  for (int s0 = t0; s0 >= 0; s0 -= 64) {
    __syncthreads();  // prev PV readers done (also covers prologue)
#pragma unroll
    for (int p = 0; p < 2; ++p) {
      const int c = tid + p * 256, r = c >> 3, c8 = (c & 7) * 8;
      *(ushortv8*)&Ks[r][c8] = *(const ushortv8*)&K[(size_t)(s0 + r) * Dn + h * Sn + c8];
      const ushortv8 vv = *(const ushortv8*)&V[(size_t)(s0 + r) * Dn + h * HDn + c8];
#pragma unroll
      for (int j = 0; j < 8; ++j) {
        const int dd = c8 + j;
        Vt[dd][((((r >> 3) ^ (dd >> 3)) & 7) << 3) | (r & 7)] = vv[j];
      }
    }
    if (tid < 64) cgS[tid] = (float)cg[(s0 + tid) * Hn + h];
    __syncthreads();

    if (s0 + 64 <= t0 && cgT[0] - cgS[63] < -80.f) break;

    // QK^T: per-wave 2x2 fragments, K=64 (2 mfma k-steps)
    floatx4 sc[2][2] = {};
#pragma unroll
    for (int kk = 0; kk < 2; ++kk) {
      short8 aq0 = *(const short8*)&Qs[(wm * 2 + 0) * 16 + l16][kk * 32 + lk * 8];
      short8 aq1 = *(const short8*)&Qs[(wm * 2 + 1) * 16 + l16][kk * 32 + lk * 8];
      short8 bk0 = *(const short8*)&Ks[(wn * 2 + 0) * 16 + l16][kk * 32 + lk * 8];
      short8 bk1 = *(const short8*)&Ks[(wn * 2 + 1) * 16 + l16][kk * 32 + lk * 8];
      sc[0][0] = __builtin_amdgcn_mfma_f32_16x16x32_bf16(aq0, bk0, sc[0][0], 0, 0, 0);
      sc[0][1] = __builtin_amdgcn_mfma_f32_16x16x32_bf16(aq0, bk1, sc[0][1], 0, 0, 0);
      sc[1][0] = __builtin_amdgcn_mfma_f32_16x16x32_bf16(aq1, bk0, sc[1][0], 0, 0, 0);
      sc[1][1] = __builtin_amdgcn_mfma_f32_16x16x32_bf16(aq1, bk1, sc[1][1], 0, 0, 0);
    }

    // gate on C fragments: col=lane&15 (s), row=(lane>>4)*4+r (t)
#pragma unroll
    for (int mi = 0; mi < 2; ++mi) {
#pragma unroll
      for (int ni = 0; ni < 2; ++ni) {
        const int s_loc = (wn * 2 + ni) * 16 + l16;
        const int s_g = s0 + s_loc;
        const float cs = cgS[s_loc];
#pragma unroll
        for (int r = 0; r < 4; ++r) {
          const int t_loc = (wm * 2 + mi) * 16 + lk * 4 + r;
          const int t_g = t0 + t_loc;
          float val = 0.f;
          if (s_g <= t_g) {
            const float dd = cgT[t_loc] - cs;
            const int xr = t_g ^ s_g;
            const int lvl = xr ? (32 - __clz(xr)) : 0;
            val = sc[mi][ni][r] * 0.125f * __expf(dd) * lamT[t_loc][lvl];
          }
          Ps[t_loc][s_loc] = f2bf(val);
        }
      }
    }
    __syncthreads();  // P ready for all waves

    // PV: A = P rows t (k=s), B = Vt rows d (k=s, XOR-swizzled k8 blocks)
#pragma unroll
    for (int kk = 0; kk < 2; ++kk) {
      short8 ap0 = *(const short8*)&Ps[(wm * 2 + 0) * 16 + l16][kk * 32 + lk * 8];
      short8 ap1 = *(const short8*)&Ps[(wm * 2 + 1) * 16 + l16][kk * 32 + lk * 8];
      const int d0 = (wn * 2 + 0) * 16 + l16;
      const int d1 = (wn * 2 + 1) * 16 + l16;
      short8 bv0 = *(const short8*)&Vt[d0][(((kk * 4 + lk) ^ (d0 >> 3)) & 7) << 3];
      short8 bv1 = *(const short8*)&Vt[d1][(((kk * 4 + lk) ^ (d1 >> 3)) & 7) << 3];
      accY[0][0] = __builtin_amdgcn_mfma_f32_16x16x32_bf16(ap0, bv0, accY[0][0], 0, 0, 0);
      accY[0][1] = __builtin_amdgcn_mfma_f32_16x16x32_bf16(ap0, bv1, accY[0][1], 0, 0, 0);
      accY[1][0] = __builtin_amdgcn_mfma_f32_16x16x32_bf16(ap1, bv0, accY[1][0], 0, 0, 0);
      accY[1][1] = __builtin_amdgcn_mfma_f32_16x16x32_bf16(ap1, bv1, accY[1][1], 0, 0, 0);
    }
  }

  // epilogue: stage Y tile (bf16) in Ps, then coalesced store
  __syncthreads();
#pragma unroll
  for (int mi = 0; mi < 2; ++mi)
#pragma unroll
    for (int ni = 0; ni < 2; ++ni)
#pragma unroll
      for (int r = 0; r < 4; ++r)
        Ps[(wm * 2 + mi) * 16 + lk * 4 + r][(wn * 2 + ni) * 16 + l16] =
            f2bf(accY[mi][ni][r]);
  __syncthreads();
#pragma unroll
  for (int p = 0; p < 2; ++p) {
    const int c = tid + p * 256, r = c >> 3, c8 = (c & 7) * 8;
    *(ushortv8*)&Y[(size_t)(t0 + r) * Dn + h * HDn + c8] = *(const ushortv8*)&Ps[r][c8];
  }
}

// ---------------- layernorm (in-place on d_out) -------------------------------
__global__ __launch_bounds__(256) void ln_k(float* __restrict__ io,
                                            const float* __restrict__ gw,
                                            const float* __restrict__ bw) {
  const int t = blockIdx.x;
  const int tid = threadIdx.x;
  const float4 v = ((const float4*)(io + t * Dn))[tid];
  float s = v.x + v.y + v.z + v.w;
  float q = v.x * v.x + v.y * v.y + v.z * v.z + v.w * v.w;
#pragma unroll
  for (int off = 32; off >= 1; off >>= 1) {
    s += __shfl_down(s, off);
    q += __shfl_down(q, off);
  }
  __shared__ float sm[4], qm[4];
  const int w = tid >> 6, lane = tid & 63;
  if (lane == 0) { sm[w] = s; qm[w] = q; }
  __syncthreads();
  const float S_ = sm[0] + sm[1] + sm[2] + sm[3];
  const float Q_ = qm[0] + qm[1] + qm[2] + qm[3];
  const float mu = S_ * (1.f / Dn);
  const float var = Q_ * (1.f / Dn) - mu * mu;
  const float inv = rsqrtf(var + 1e-5f);
  const float4 gg = ((const float4*)gw)[tid];
  const float4 bb = ((const float4*)bw)[tid];
  float4 o;
  o.x = (v.x - mu) * inv * gg.x + bb.x;
  o.y = (v.y - mu) * inv * gg.y + bb.y;
  o.z = (v.z - mu) * inv * gg.z + bb.z;
  o.w = (v.w - mu) * inv * gg.w + bb.w;
  ((float4*)(io + t * Dn))[tid] = o;
}

extern "C" void kernel_launch(void* const* d_in, const int* in_sizes, int n_in,
                              void* d_out, int out_size, void* d_ws, size_t ws_size,
                              hipStream_t stream) {
  (void)in_sizes; (void)n_in; (void)out_size; (void)ws_size;
  const float* x      = (const float*)d_in[0];
  const float* Wq     = (const float*)d_in[1];
  const float* Wk     = (const float*)d_in[2];
  const float* Wv     = (const float*)d_in[3];
  const float* Wdl    = (const float*)d_in[4];
  const float* Wdt    = (const float*)d_in[5];
  const float* Wout   = (const float*)d_in[6];
  const float* A_log  = (const float*)d_in[7];
  const float* dt_bias= (const float*)d_in[8];
  const float* Lp     = (const float*)d_in[9];
  const float* ln_g   = (const float*)d_in[10];
  const float* ln_b   = (const float*)d_in[11];
  float* out = (float*)d_out;
  float* ws  = (float*)d_ws;

  const size_t MAT = (size_t)Tn * Dn;   // 2,097,152
  const size_t WSZ = (size_t)Dn * Dn;   // 1,048,576
  size_t off = 0;
  float*  gb   = ws + off; off += (size_t)Tn * Hn;
  double* cgd  = (double*)(ws + off); off += 2 * (size_t)Tn * Hn;
  float*  dlb  = ws + off; off += (size_t)Tn * 256;
  unsigned short* xb16 = (unsigned short*)(ws + off); off += MAT / 2;
  unsigned short* Wq16 = (unsigned short*)(ws + off); off += WSZ / 2;
  unsigned short* Wk16 = (unsigned short*)(ws + off); off += WSZ / 2;
  unsigned short* Wv16 = (unsigned short*)(ws + off); off += WSZ / 2;
  unsigned short* Wo16 = (unsigned short*)(ws + off); off += WSZ / 2;
  unsigned short* Ws16 = (unsigned short*)(ws + off); off += (size_t)256 * Dn / 2;
  unsigned short* Q16  = (unsigned short*)(ws + off); off += MAT / 2;
  unsigned short* K16  = (unsigned short*)(ws + off); off += MAT / 2;
  unsigned short* V16  = (unsigned short*)(ws + off); off += MAT / 2;
  unsigned short* Y16  = (unsigned short*)(ws + off); off += MAT / 2;

  // 1. bf16 conversions
  cvt1_k<<<dim3(MAT / 2048), 256, 0, stream>>>(x, xb16);
  cvt4_k<<<dim3(WSZ / 2048, 4), 256, 0, stream>>>(
      Wq, Wq16, Wk, Wk16, Wv, Wv16, Wout, Wo16);
  cvt_wsmall_k<<<dim3(256 * Dn / 2048), 256, 0, stream>>>(Wdl, Ws16);
  // 2. Q/K/V projections (bf16 MFMA, bf16 output)
  mfma_gemm_k<<<dim3(Tn / 128, Dn / 128, 3), 256, 0, stream>>>(
      xb16, Wq16, Wk16, Wv16, nullptr,
      (float*)Q16, (float*)K16, (float*)V16, Dn, 1);
  // 3. dl projection (bf16 MFMA, fp32 output, N=256 padded)
  mfma_gemm_k<<<dim3(Tn / 128, 2, 1), 256, 0, stream>>>(
      xb16, Ws16, nullptr, nullptr, nullptr, dlb, nullptr, nullptr, 256, 0);
  // 4. dt projection (fp32) + per-head cumsum
  dt_k<<<dim3(Tn / 8), 256, 0, stream>>>(x, Wdt, A_log, dt_bias, gb);
  scan_k<<<dim3(Hn), 256, 0, stream>>>(gb, cgd);
  // 5. attention core (bf16 MFMA), writes Y bf16
  attn_k<<<dim3(Tn / 64, Hn), 256, 0, stream>>>(Q16, K16, V16, cgd, dlb, Lp, Y16);
  // 6. out-proj + residual (bf16 MFMA, fp32 out), layernorm
  mfma_gemm_k<<<dim3(Tn / 128, Dn / 128, 1), 256, 0, stream>>>(
      Y16, Wo16, nullptr, nullptr, x, out, nullptr, nullptr, Dn, 0);
  ln_k<<<dim3(Tn), 256, 0, stream>>>(out, ln_g, ln_b);
}

// Round 7
// 121.386 us; speedup vs baseline: 7.5435x; 1.2277x over previous
//
#include <hip/hip_runtime.h>
#include <math.h>

#define Tn 2048
#define Dn 1024
#define Hn 16
#define Sn 64
#define LVn 12
#define HDn 64
#define NQKV 3328   // 1024 Q + 1024 K + 1024 V + 256 dl(padded)

typedef short short8 __attribute__((ext_vector_type(8)));
typedef unsigned short ushortv8 __attribute__((ext_vector_type(8)));
typedef float floatx4 __attribute__((ext_vector_type(4)));

__device__ __forceinline__ float softplus_f(float z) {
  return (z > 0.f) ? (z + log1pf(expf(-z))) : log1pf(expf(z));
}

__device__ __forceinline__ unsigned short f2bf(float f) {
  union { float f; unsigned u; } v; v.f = f;
  unsigned r = v.u + 0x7FFF + ((v.u >> 16) & 1);  // RNE
  return (unsigned short)(r >> 16);
}

__device__ __forceinline__ void cvt8(const float* s, unsigned short* d) {
  const float4 u0 = *(const float4*)s;
  const float4 u1 = *(const float4*)(s + 4);
  ushortv8 o;
  o[0] = f2bf(u0.x); o[1] = f2bf(u0.y); o[2] = f2bf(u0.z); o[3] = f2bf(u0.w);
  o[4] = f2bf(u1.x); o[5] = f2bf(u1.y); o[6] = f2bf(u1.z); o[7] = f2bf(u1.w);
  *(ushortv8*)d = o;
}

__device__ __forceinline__ void gld16(const void* g, void* l) {
  __builtin_amdgcn_global_load_lds(
      (const __attribute__((address_space(1))) unsigned int*)g,
      (__attribute__((address_space(3))) unsigned int*)l, 16, 0, 0);
}

// ---------------- fused fp32 -> bf16 conversion --------------------------------
// chunks: [0,1024) x -> xb16 ; [1024,2688) Wcat (3328 rows) ; [2688,3200) Wout
__global__ __launch_bounds__(256) void cvt_all_k(
    const float* __restrict__ x, const float* __restrict__ Wq,
    const float* __restrict__ Wk, const float* __restrict__ Wv,
    const float* __restrict__ Wdl, const float* __restrict__ Wout,
    unsigned short* __restrict__ xb, unsigned short* __restrict__ wcat,
    unsigned short* __restrict__ wob) {
  const int chunk = blockIdx.x;
  const int eo = threadIdx.x * 8;
  if (chunk < 1024) {
    const int e = chunk * 2048 + eo;
    cvt8(&x[e], &xb[e]);
  } else if (chunk < 2688) {
    const int e = (chunk - 1024) * 2048 + eo;
    const int row = e >> 10, col = e & 1023;
    if (row < 1024)       cvt8(&Wq[(size_t)row * 1024 + col], &wcat[e]);
    else if (row < 2048)  cvt8(&Wk[(size_t)(row - 1024) * 1024 + col], &wcat[e]);
    else if (row < 3072)  cvt8(&Wv[(size_t)(row - 2048) * 1024 + col], &wcat[e]);
    else if (row < 3264)  cvt8(&Wdl[(size_t)(row - 3072) * 1024 + col], &wcat[e]);
    else                  *(ushortv8*)&wcat[e] = (ushortv8)0;
  } else {
    const int e = (chunk - 2688) * 2048 + eo;
    cvt8(&Wout[e], &wob[e]);
  }
}

// ---------------- bf16 MFMA GEMM ----------------------------------------------
// C[m][n] = sum_k A[m][k]*B[n][k]. 128x128 tile, BK=32, 4 waves, 16x16x32 MFMA.
// mode 0: fp32 out to Cf (ldc), optional +R.   mode 2: qkv/dl split:
//   col<3072 -> bf16 to Cb (ld 3072); col>=3072 -> fp32 to Cf (ld 256, col-3072).
__global__ __launch_bounds__(256) void mfma_gemm_k(
    const unsigned short* __restrict__ A, const unsigned short* __restrict__ B,
    const float* __restrict__ R, unsigned short* __restrict__ Cb,
    float* __restrict__ Cf, int ldc, int mode) {
  __shared__ unsigned short lA[128 * 32];
  __shared__ unsigned short lB[128 * 32];
  const int tid = threadIdx.x;
  const int bm = blockIdx.x * 128, bn = blockIdx.y * 128;
  const int lane = tid & 63, wave = tid >> 6;
  const int wm = wave >> 1, wn = wave & 1;
  const int l16 = lane & 15, lk = lane >> 4;
  const int sr = tid >> 2, sc = (tid & 3) * 8;
  floatx4 acc[4][4] = {};
  for (int k0 = 0; k0 < Dn; k0 += 32) {
    __syncthreads();
    gld16(&A[(size_t)(bm + sr) * Dn + k0 + sc],      &lA[tid * 8]);
    gld16(&A[(size_t)(bm + 64 + sr) * Dn + k0 + sc], &lA[2048 + tid * 8]);
    gld16(&B[(size_t)(bn + sr) * Dn + k0 + sc],      &lB[tid * 8]);
    gld16(&B[(size_t)(bn + 64 + sr) * Dn + k0 + sc], &lB[2048 + tid * 8]);
    __syncthreads();
    short8 a[4], b[4];
#pragma unroll
    for (int mf = 0; mf < 4; ++mf)
      a[mf] = *(const short8*)&lA[(wm * 64 + mf * 16 + l16) * 32 + lk * 8];
#pragma unroll
    for (int nf = 0; nf < 4; ++nf)
      b[nf] = *(const short8*)&lB[(wn * 64 + nf * 16 + l16) * 32 + lk * 8];
#pragma unroll
    for (int mf = 0; mf < 4; ++mf)
#pragma unroll
      for (int nf = 0; nf < 4; ++nf)
        acc[mf][nf] = __builtin_amdgcn_mfma_f32_16x16x32_bf16(
            a[mf], b[nf], acc[mf][nf], 0, 0, 0);
  }
#pragma unroll
  for (int mf = 0; mf < 4; ++mf) {
#pragma unroll
    for (int nf = 0; nf < 4; ++nf) {
      const int col = bn + wn * 64 + nf * 16 + l16;
#pragma unroll
      for (int r = 0; r < 4; ++r) {
        const int row = bm + wm * 64 + mf * 16 + lk * 4 + r;
        float v = acc[mf][nf][r];
        if (mode == 0) {
          if (R) v += R[(size_t)row * ldc + col];
          Cf[(size_t)row * ldc + col] = v;
        } else {
          if (col < 3072) Cb[(size_t)row * 3072 + col] = f2bf(v);
          else            Cf[(size_t)row * 256 + (col - 3072)] = v;
        }
      }
    }
  }
}

// ---------------- dt projection (fp32, precision-critical) -------------------
__global__ __launch_bounds__(256) void dt_k(
    const float* __restrict__ x, const float* __restrict__ Wdt,
    const float* __restrict__ A_log, const float* __restrict__ dt_bias,
    float* __restrict__ g) {
  const int t0 = blockIdx.x * 8;
  __shared__ float xs[8][Dn];
  const int tid = threadIdx.x;
#pragma unroll
  for (int i = 0; i < 8; ++i)
    ((float4*)xs[i])[tid] = ((const float4*)&x[(size_t)(t0 + i) * Dn])[tid];
  __syncthreads();
  const int d = tid >> 1, half = tid & 1;
  const int tl = d >> 4, h = d & 15;
  const float4* xr = (const float4*)&xs[tl][half * 512];
  const float4* wr = (const float4*)&Wdt[h * Dn + half * 512];
  float acc = 0.f;
#pragma unroll 4
  for (int k = 0; k < 128; ++k) {
    const float4 a = xr[k], b = wr[k];
    acc += a.x * b.x + a.y * b.y + a.z * b.z + a.w * b.w;
  }
  acc += __shfl_xor(acc, 1);
  if (half == 0) {
    const float dtv = softplus_f(acc + dt_bias[h]);
    g[(t0 + tl) * Hn + h] = -expf(A_log[h]) * dtv;
  }
}

// ---------------- per-head parallel cumsum (double) --------------------------
__global__ __launch_bounds__(256) void scan_k(const float* __restrict__ g,
                                              double* __restrict__ cg) {
  const int h = blockIdx.x;
  const int tid = threadIdx.x;
  double v[8];
  double run = 0.0;
#pragma unroll
  for (int i = 0; i < 8; ++i) {
    run += (double)g[(tid * 8 + i) * Hn + h];
    v[i] = run;
  }
  __shared__ double ls[256];
  ls[tid] = run;
  __syncthreads();
  for (int off = 1; off < 256; off <<= 1) {
    double add = (tid >= off) ? ls[tid - off] : 0.0;
    __syncthreads();
    ls[tid] += add;
    __syncthreads();
  }
  const double excl = ls[tid] - run;
#pragma unroll
  for (int i = 0; i < 8; ++i) cg[(tid * 8 + i) * Hn + h] = excl + v[i];
}

// ---------------- gated causal attention core (bf16 MFMA) --------------------
// QKV packed bf16 [2048][3072]: Q at col h*64, K at 1024+h*64, V at 2048+h*64.
__global__ __launch_bounds__(256) void attn_k(
    const unsigned short* __restrict__ QKV, const double* __restrict__ cg,
    const float* __restrict__ dlb, const float* __restrict__ Lp,
    unsigned short* __restrict__ Y) {
  const int h = blockIdx.y;
  const int t0 = blockIdx.x * 64;
  __shared__ unsigned short Qs[64][72], Ks[64][72], Ps[64][72], Vt[64][72];
  __shared__ float cgT[64], cgS[64];
  __shared__ float lamT[64][LVn];
  const int tid = threadIdx.x;
  const int lane = tid & 63, wave = tid >> 6;
  const int wm = wave >> 1, wn = wave & 1;
  const int l16 = lane & 15, lk = lane >> 4;
  const unsigned short* Q = QKV + h * Sn;
  const unsigned short* K = QKV + 1024 + h * Sn;
  const unsigned short* V = QKV + 2048 + h * HDn;

#pragma unroll
  for (int p = 0; p < 2; ++p) {
    const int c = tid + p * 256, r = c >> 3, c8 = (c & 7) * 8;
    *(ushortv8*)&Qs[r][c8] = *(const ushortv8*)&Q[(size_t)(t0 + r) * 3072 + c8];
  }
  if (tid < 64) cgT[tid] = (float)cg[(t0 + tid) * Hn + h];
  for (int i = tid; i < 64 * LVn; i += 256) {
    const int r = i / LVn, l = i % LVn;
    lamT[r][l] = softplus_f(Lp[h * LVn + l] * dlb[(size_t)(t0 + r) * 256 + h * LVn + l]);
  }

  floatx4 accY[2][2] = {};

  for (int s0 = t0; s0 >= 0; s0 -= 64) {
    __syncthreads();  // prev readers done (also covers prologue)
#pragma unroll
    for (int p = 0; p < 2; ++p) {
      const int c = tid + p * 256, r = c >> 3, c8 = (c & 7) * 8;
      *(ushortv8*)&Ks[r][c8] = *(const ushortv8*)&K[(size_t)(s0 + r) * 3072 + c8];
      const ushortv8 vv = *(const ushortv8*)&V[(size_t)(s0 + r) * 3072 + c8];
#pragma unroll
      for (int j = 0; j < 8; ++j) {
        const int dd = c8 + j;
        Vt[dd][((((r >> 3) ^ (dd >> 3)) & 7) << 3) | (r & 7)] = vv[j];
      }
    }
    if (tid < 64) cgS[tid] = (float)cg[(s0 + tid) * Hn + h];
    __syncthreads();

    if (s0 + 64 <= t0 && cgT[0] - cgS[63] < -80.f) break;

    // QK^T: per-wave 2x2 fragments, K=64 (2 mfma k-steps)
    floatx4 sc[2][2] = {};
#pragma unroll
    for (int kk = 0; kk < 2; ++kk) {
      short8 aq0 = *(const short8*)&Qs[(wm * 2 + 0) * 16 + l16][kk * 32 + lk * 8];
      short8 aq1 = *(const short8*)&Qs[(wm * 2 + 1) * 16 + l16][kk * 32 + lk * 8];
      short8 bk0 = *(const short8*)&Ks[(wn * 2 + 0) * 16 + l16][kk * 32 + lk * 8];
      short8 bk1 = *(const short8*)&Ks[(wn * 2 + 1) * 16 + l16][kk * 32 + lk * 8];
      sc[0][0] = __builtin_amdgcn_mfma_f32_16x16x32_bf16(aq0, bk0, sc[0][0], 0, 0, 0);
      sc[0][1] = __builtin_amdgcn_mfma_f32_16x16x32_bf16(aq0, bk1, sc[0][1], 0, 0, 0);
      sc[1][0] = __builtin_amdgcn_mfma_f32_16x16x32_bf16(aq1, bk0, sc[1][0], 0, 0, 0);
      sc[1][1] = __builtin_amdgcn_mfma_f32_16x16x32_bf16(aq1, bk1, sc[1][1], 0, 0, 0);
    }

    // gate on C fragments: col=lane&15 (s), row=(lane>>4)*4+r (t)
#pragma unroll
    for (int mi = 0; mi < 2; ++mi) {
#pragma unroll
      for (int ni = 0; ni < 2; ++ni) {
        const int s_loc = (wn * 2 + ni) * 16 + l16;
        const int s_g = s0 + s_loc;
        const float cs = cgS[s_loc];
#pragma unroll
        for (int r = 0; r < 4; ++r) {
          const int t_loc = (wm * 2 + mi) * 16 + lk * 4 + r;
          const int t_g = t0 + t_loc;
          float val = 0.f;
          if (s_g <= t_g) {
            const float dd = cgT[t_loc] - cs;
            const int xr = t_g ^ s_g;
            const int lvl = xr ? (32 - __clz(xr)) : 0;
            val = sc[mi][ni][r] * 0.125f * __expf(dd) * lamT[t_loc][lvl];
          }
          Ps[t_loc][s_loc] = f2bf(val);
        }
      }
    }
    __syncthreads();  // P ready for all waves

    // PV: A = P rows t (k=s), B = Vt rows d (k=s, XOR-swizzled k8 blocks)
#pragma unroll
    for (int kk = 0; kk < 2; ++kk) {
      short8 ap0 = *(const short8*)&Ps[(wm * 2 + 0) * 16 + l16][kk * 32 + lk * 8];
      short8 ap1 = *(const short8*)&Ps[(wm * 2 + 1) * 16 + l16][kk * 32 + lk * 8];
      const int d0 = (wn * 2 + 0) * 16 + l16;
      const int d1 = (wn * 2 + 1) * 16 + l16;
      short8 bv0 = *(const short8*)&Vt[d0][(((kk * 4 + lk) ^ (d0 >> 3)) & 7) << 3];
      short8 bv1 = *(const short8*)&Vt[d1][(((kk * 4 + lk) ^ (d1 >> 3)) & 7) << 3];
      accY[0][0] = __builtin_amdgcn_mfma_f32_16x16x32_bf16(ap0, bv0, accY[0][0], 0, 0, 0);
      accY[0][1] = __builtin_amdgcn_mfma_f32_16x16x32_bf16(ap0, bv1, accY[0][1], 0, 0, 0);
      accY[1][0] = __builtin_amdgcn_mfma_f32_16x16x32_bf16(ap1, bv0, accY[1][0], 0, 0, 0);
      accY[1][1] = __builtin_amdgcn_mfma_f32_16x16x32_bf16(ap1, bv1, accY[1][1], 0, 0, 0);
    }
  }

  // epilogue: stage Y tile (bf16) in Ps, then coalesced store
  __syncthreads();
#pragma unroll
  for (int mi = 0; mi < 2; ++mi)
#pragma unroll
    for (int ni = 0; ni < 2; ++ni)
#pragma unroll
      for (int r = 0; r < 4; ++r)
        Ps[(wm * 2 + mi) * 16 + lk * 4 + r][(wn * 2 + ni) * 16 + l16] =
            f2bf(accY[mi][ni][r]);
  __syncthreads();
#pragma unroll
  for (int p = 0; p < 2; ++p) {
    const int c = tid + p * 256, r = c >> 3, c8 = (c & 7) * 8;
    *(ushortv8*)&Y[(size_t)(t0 + r) * Dn + h * HDn + c8] = *(const ushortv8*)&Ps[r][c8];
  }
}

// ---------------- layernorm (in-place on d_out) -------------------------------
__global__ __launch_bounds__(256) void ln_k(float* __restrict__ io,
                                            const float* __restrict__ gw,
                                            const float* __restrict__ bw) {
  const int t = blockIdx.x;
  const int tid = threadIdx.x;
  const float4 v = ((const float4*)(io + t * Dn))[tid];
  float s = v.x + v.y + v.z + v.w;
  float q = v.x * v.x + v.y * v.y + v.z * v.z + v.w * v.w;
#pragma unroll
  for (int off = 32; off >= 1; off >>= 1) {
    s += __shfl_down(s, off);
    q += __shfl_down(q, off);
  }
  __shared__ float sm[4], qm[4];
  const int w = tid >> 6, lane = tid & 63;
  if (lane == 0) { sm[w] = s; qm[w] = q; }
  __syncthreads();
  const float S_ = sm[0] + sm[1] + sm[2] + sm[3];
  const float Q_ = qm[0] + qm[1] + qm[2] + qm[3];
  const float mu = S_ * (1.f / Dn);
  const float var = Q_ * (1.f / Dn) - mu * mu;
  const float inv = rsqrtf(var + 1e-5f);
  const float4 gg = ((const float4*)gw)[tid];
  const float4 bb = ((const float4*)bw)[tid];
  float4 o;
  o.x = (v.x - mu) * inv * gg.x + bb.x;
  o.y = (v.y - mu) * inv * gg.y + bb.y;
  o.z = (v.z - mu) * inv * gg.z + bb.z;
  o.w = (v.w - mu) * inv * gg.w + bb.w;
  ((float4*)(io + t * Dn))[tid] = o;
}

extern "C" void kernel_launch(void* const* d_in, const int* in_sizes, int n_in,
                              void* d_out, int out_size, void* d_ws, size_t ws_size,
                              hipStream_t stream) {
  (void)in_sizes; (void)n_in; (void)out_size; (void)ws_size;
  const float* x      = (const float*)d_in[0];
  const float* Wq     = (const float*)d_in[1];
  const float* Wk     = (const float*)d_in[2];
  const float* Wv     = (const float*)d_in[3];
  const float* Wdl    = (const float*)d_in[4];
  const float* Wdt    = (const float*)d_in[5];
  const float* Wout   = (const float*)d_in[6];
  const float* A_log  = (const float*)d_in[7];
  const float* dt_bias= (const float*)d_in[8];
  const float* Lp     = (const float*)d_in[9];
  const float* ln_g   = (const float*)d_in[10];
  const float* ln_b   = (const float*)d_in[11];
  float* out = (float*)d_out;
  float* ws  = (float*)d_ws;

  const size_t MAT = (size_t)Tn * Dn;   // 2,097,152
  const size_t WSZ = (size_t)Dn * Dn;   // 1,048,576
  size_t off = 0;
  float*  gb   = ws + off; off += (size_t)Tn * Hn;
  double* cgd  = (double*)(ws + off); off += 2 * (size_t)Tn * Hn;
  float*  dlb  = ws + off; off += (size_t)Tn * 256;
  unsigned short* xb16  = (unsigned short*)(ws + off); off += MAT / 2;
  unsigned short* Wcat16= (unsigned short*)(ws + off); off += (size_t)NQKV * Dn / 2;
  unsigned short* Wo16  = (unsigned short*)(ws + off); off += WSZ / 2;
  unsigned short* QKV16 = (unsigned short*)(ws + off); off += (size_t)Tn * 3072 / 2;
  unsigned short* Y16   = (unsigned short*)(ws + off); off += MAT / 2;

  // 1. fused bf16 conversions (x, Wcat=[Wq;Wk;Wv;Wdl;0], Wout)
  cvt_all_k<<<dim3(3200), 256, 0, stream>>>(x, Wq, Wk, Wv, Wdl, Wout,
                                            xb16, Wcat16, Wo16);
  // 2. fused QKV + dl projection (bf16 MFMA; bf16 QKV out, fp32 dl out)
  mfma_gemm_k<<<dim3(Tn / 128, NQKV / 128), 256, 0, stream>>>(
      xb16, Wcat16, nullptr, QKV16, dlb, 0, 2);
  // 3. dt projection (fp32) + per-head cumsum
  dt_k<<<dim3(Tn / 8), 256, 0, stream>>>(x, Wdt, A_log, dt_bias, gb);
  scan_k<<<dim3(Hn), 256, 0, stream>>>(gb, cgd);
  // 4. attention core (bf16 MFMA), writes Y bf16
  attn_k<<<dim3(Tn / 64, Hn), 256, 0, stream>>>(QKV16, cgd, dlb, Lp, Y16);
  // 5. out-proj + residual (bf16 MFMA, fp32 out), layernorm
  mfma_gemm_k<<<dim3(Tn / 128, Dn / 128), 256, 0, stream>>>(
      Y16, Wo16, x, nullptr, out, Dn, 0);
  ln_k<<<dim3(Tn), 256, 0, stream>>>(out, ln_g, ln_b);
}